// Round 1
// baseline (2872.641 us; speedup 1.0000x reference)
//
#include <hip/hip_runtime.h>
#include <stdint.h>

#define D_EMB 512
#define D_DEC 1024
#define VOCAB 32000
#define BATCH 64
#define STEPS 64

// k_logits grid split: first GH_BLOCKS blocks compute gh(t+1)=h(t)@w_hh^T+b_hh,
// the remaining LOG_BLOCKS-GH_BLOCKS blocks do the vocab GEMV + argmax.
#define LOG_BLOCKS 1024
#define GH_BLOCKS  88
#define VOC_BLOCKS (LOG_BLOCKS - GH_BLOCKS)   // 936
#define NBB        VOC_BLOCKS                 // per-block argmax slots

typedef float f32x4 __attribute__((ext_vector_type(4)));

// Workspace (poisoned 0xAA before every call; every field fully rewritten
// each call before first read).
struct Ws {
    float h[2][D_DEC];                 // ping-pong GRU state (B=1: batch rows identical)
    float gh[3 * D_DEC];               // h(t-1)@w_hh^T + b_hh, produced by k_logits(t-1)
    float logits[VOCAB];               // logits of current step (B=1)
    unsigned long long bbest[NBB];     // per-vocab-block packed argmax (key|~idx)
};

// Monotone map: float order -> unsigned order; low word = ~idx so that
// max tie-breaks toward the SMALLEST index (numpy argmax rule).
__device__ __forceinline__ unsigned long long pack_lv(float f, int v) {
    unsigned u = __float_as_uint(f);
    unsigned key = (u & 0x80000000u) ? ~u : (u | 0x80000000u);
    return ((unsigned long long)key << 32) | (unsigned)(0xFFFFFFFFu - (unsigned)v);
}
__device__ __forceinline__ int unpack_v(unsigned long long p) {
    return (int)(0xFFFFFFFFu - (unsigned)(p & 0xFFFFFFFFu));
}

// ---------------------------------------------------------------------------
// K1: per step t:
//   (a) reduce bbest -> pred(t-1) (block-local, no atomics)
//   (b) broadcast logits(t-1)/pred(t-1) to all 64 batch rows (non-temporal)
//   (c) GRU update for step t: only the pred-dependent x@w_ih^T part; the
//       h-dependent gh part was precomputed by k_logits(t-1). At t==0 the gh
//       part is computed inline from `init`.
// At t==STEPS: (a)+(b) only.
// ---------------------------------------------------------------------------
__global__ __launch_bounds__(256) void k_gates(
    const float* __restrict__ embs, const float* __restrict__ init,
    const float* __restrict__ w_ih, const float* __restrict__ w_hh,
    const float* __restrict__ b_ih, const float* __restrict__ b_hh,
    const int* __restrict__ bos_idx,
    float* __restrict__ out_logits, float* __restrict__ out_preds,
    Ws* __restrict__ ws, int t)
{
    const int tid  = threadIdx.x;
    const int lane = tid & 63;
    const int widx = tid >> 6;
    const int gtid = blockIdx.x * 256 + tid;
    const int nthr = gridDim.x * 256;
    const int wid  = gtid >> 6;          // 0..1023 with grid 256x256

    __shared__ unsigned long long sb[4];

    // ---- phase A: per-thread scan of bbest (loads overlap phase B) ----
    if (t > 0) {
        unsigned long long bb = 0ull;
        for (int i = tid; i < NBB; i += 256) {
            unsigned long long p = ws->bbest[i];
            if (p > bb) bb = p;
        }
        #pragma unroll
        for (int off = 32; off > 0; off >>= 1) {
            unsigned long long o = __shfl_down(bb, off, 64);
            if (o > bb) bb = o;
        }
        if (lane == 0) sb[widx] = bb;

        // ---- phase B: broadcast logits(t-1) to 64 batch rows (nt stores) ----
        const f32x4* lb = (const f32x4*)ws->logits;   // 8000 float4, L2-hot
        f32x4* ob = (f32x4*)out_logits;
        const int VQ = VOCAB / 4;                     // 8000
        for (int idx = gtid; idx < BATCH * VQ; idx += nthr) {
            int b = idx / VQ;
            int c = idx - b * VQ;
            __builtin_nontemporal_store(
                lb[c], &ob[(size_t)b * (STEPS * (size_t)VQ) + (size_t)(t - 1) * VQ + c]);
        }
    }

    // ---- phase C: finalize pred ----
    int pred;
    if (t == 0) {
        pred = *bos_idx;
    } else {
        __syncthreads();
        unsigned long long m = sb[0];
        #pragma unroll
        for (int i = 1; i < 4; ++i) if (sb[i] > m) m = sb[i];
        pred = unpack_v(m);
        if (gtid < BATCH)
            __builtin_nontemporal_store((float)pred, &out_preds[gtid * STEPS + (t - 1)]);
    }

    if (t >= STEPS) return;   // final launch: broadcast only

    // ---- GRU cell, wave-per-j (x-dependent part only for t>0) ----
    const int j = wid;
    if (j >= D_DEC) return;

    const float* hprev = (t == 0) ? init : ws->h[(t + 1) & 1];
    const float4* x4   = (const float4*)(embs + (size_t)pred * D_EMB);  // 128 float4
    const float4* wih4 = (const float4*)w_ih;                           // row = 128 float4

    float s_ir = 0.f, s_iz = 0.f, s_in = 0.f;
    #pragma unroll
    for (int k0 = 0; k0 < 2; ++k0) {
        int k = k0 * 64 + lane;
        float4 xv = x4[k];
        float4 a = wih4[(size_t)j * 128 + k];
        float4 b = wih4[(size_t)(j + D_DEC) * 128 + k];
        float4 c = wih4[(size_t)(j + 2 * D_DEC) * 128 + k];
        s_ir += a.x * xv.x + a.y * xv.y + a.z * xv.z + a.w * xv.w;
        s_iz += b.x * xv.x + b.y * xv.y + b.z * xv.z + b.w * xv.w;
        s_in += c.x * xv.x + c.y * xv.y + c.z * xv.z + c.w * xv.w;
    }

    float s_hr = 0.f, s_hz = 0.f, s_hn = 0.f;
    if (t == 0) {
        // one-time: gh(0) from init (k_logits hasn't run yet)
        const float4* h4   = (const float4*)hprev;    // 256 float4
        const float4* whh4 = (const float4*)w_hh;     // row = 256 float4
        #pragma unroll
        for (int k0 = 0; k0 < 4; ++k0) {
            int k = k0 * 64 + lane;
            float4 hv = h4[k];
            float4 a = whh4[(size_t)j * 256 + k];
            float4 b = whh4[(size_t)(j + D_DEC) * 256 + k];
            float4 c = whh4[(size_t)(j + 2 * D_DEC) * 256 + k];
            s_hr += a.x * hv.x + a.y * hv.y + a.z * hv.z + a.w * hv.w;
            s_hz += b.x * hv.x + b.y * hv.y + b.z * hv.z + b.w * hv.w;
            s_hn += c.x * hv.x + c.y * hv.y + c.z * hv.z + c.w * hv.w;
        }
    }

    #pragma unroll
    for (int off = 32; off > 0; off >>= 1) {
        s_ir += __shfl_down(s_ir, off, 64);
        s_iz += __shfl_down(s_iz, off, 64);
        s_in += __shfl_down(s_in, off, 64);
        if (t == 0) {
            s_hr += __shfl_down(s_hr, off, 64);
            s_hz += __shfl_down(s_hz, off, 64);
            s_hn += __shfl_down(s_hn, off, 64);
        }
    }

    if (lane == 0) {
        float ir  = s_ir + b_ih[j];
        float iz  = s_iz + b_ih[j + D_DEC];
        float in_ = s_in + b_ih[j + 2 * D_DEC];
        float hr_, hz_, hn_;
        if (t == 0) {
            hr_ = s_hr + b_hh[j];
            hz_ = s_hz + b_hh[j + D_DEC];
            hn_ = s_hn + b_hh[j + 2 * D_DEC];
        } else {
            hr_ = ws->gh[j];                 // already includes b_hh
            hz_ = ws->gh[j + D_DEC];
            hn_ = ws->gh[j + 2 * D_DEC];
        }
        float r = 1.f / (1.f + expf(-(ir + hr_)));
        float z = 1.f / (1.f + expf(-(iz + hz_)));
        float n = tanhf(in_ + r * hn_);
        ws->h[t & 1][j] = (1.f - z) * n + z * hprev[j];
    }
}

// ---------------------------------------------------------------------------
// K2: logits GEMV (32000 x 1024) + argmax for step t from ws->h[t&1],
// plus gh(t+1) = h(t)@w_hh^T + b_hh (fused, off the k_gates critical path).
// Layout: 16 lanes per row, 4 rows per wave -> 16 independent loads in
// flight per lane; h staged in LDS; 4 shfl_xor per 4 rows for the reduce.
// Per-block argmax written to ws->bbest (no atomics).
// ---------------------------------------------------------------------------
__global__ __launch_bounds__(256, 4) void k_logits(
    const float* __restrict__ W_out, const float* __restrict__ b_out,
    const float* __restrict__ w_hh, const float* __restrict__ b_hh,
    Ws* __restrict__ ws, int t)
{
    const int tid  = threadIdx.x;
    const int lane = tid & 63;
    const int widx = tid >> 6;
    const int sub  = lane & 15;      // position within row
    const int grp  = lane >> 4;      // which of the 4 rows

    __shared__ float4 sh[256];                 // h(t), 1024 floats
    __shared__ unsigned long long sb[4];

    const float4* h4 = (const float4*)ws->h[t & 1];
    sh[tid] = h4[tid];
    __syncthreads();

    if (blockIdx.x < GH_BLOCKS) {
        // ---- gh role: 3072 rows of w_hh ----
        const int gw  = blockIdx.x * 4 + widx;
        const int ngw = GH_BLOCKS * 4;
        const float4* whh4 = (const float4*)w_hh;
        for (int g0 = gw * 4; g0 < 3 * D_DEC; g0 += ngw * 4) {
            const int g = g0 + grp;
            const float4* row = whh4 + (size_t)g * 256;
            float s = 0.f;
            #pragma unroll
            for (int k = 0; k < 16; ++k) {
                float4 w  = row[sub + k * 16];
                float4 hv = sh[sub + k * 16];
                s += w.x * hv.x + w.y * hv.y + w.z * hv.z + w.w * hv.w;
            }
            s += __shfl_xor(s, 1, 64);
            s += __shfl_xor(s, 2, 64);
            s += __shfl_xor(s, 4, 64);
            s += __shfl_xor(s, 8, 64);
            if (sub == 0) ws->gh[g] = s + b_hh[g];
        }
        return;
    }

    // ---- vocab role ----
    const int vw  = (blockIdx.x - GH_BLOCKS) * 4 + widx;
    const int nvw = VOC_BLOCKS * 4;
    const float4* W4 = (const float4*)W_out;   // row = 256 float4

    unsigned long long best = 0ull;
    for (int v0 = vw * 4; v0 < VOCAB; v0 += nvw * 4) {
        const int v = v0 + grp;
        const float4* row = W4 + (size_t)v * 256;
        float s = 0.f;
        #pragma unroll
        for (int k = 0; k < 16; ++k) {
            float4 w  = row[sub + k * 16];
            float4 hv = sh[sub + k * 16];
            s += w.x * hv.x + w.y * hv.y + w.z * hv.z + w.w * hv.w;
        }
        s += __shfl_xor(s, 1, 64);
        s += __shfl_xor(s, 2, 64);
        s += __shfl_xor(s, 4, 64);
        s += __shfl_xor(s, 8, 64);
        if (sub == 0) {
            float logit = s + b_out[v];
            ws->logits[v] = logit;
            unsigned long long p = pack_lv(logit, v);
            if (p > best) best = p;
        }
    }

    #pragma unroll
    for (int off = 32; off > 0; off >>= 1) {
        unsigned long long o = __shfl_down(best, off, 64);
        if (o > best) best = o;
    }
    if (lane == 0) sb[widx] = best;
    __syncthreads();
    if (tid == 0) {
        unsigned long long m = sb[0];
        #pragma unroll
        for (int i = 1; i < 4; ++i) if (sb[i] > m) m = sb[i];
        ws->bbest[blockIdx.x - GH_BLOCKS] = m;
    }
}

extern "C" void kernel_launch(void* const* d_in, const int* in_sizes, int n_in,
                              void* d_out, int out_size, void* d_ws, size_t ws_size,
                              hipStream_t stream) {
    const float* embs  = (const float*)d_in[0];
    const float* init  = (const float*)d_in[1];
    const float* w_ih  = (const float*)d_in[2];
    const float* w_hh  = (const float*)d_in[3];
    const float* b_ih  = (const float*)d_in[4];
    const float* b_hh  = (const float*)d_in[5];
    const float* W_out = (const float*)d_in[6];
    const float* b_out = (const float*)d_in[7];
    const int*   bos   = (const int*)d_in[8];

    float* out_logits = (float*)d_out;                                   // [B, T, V]
    float* out_preds  = out_logits + (size_t)BATCH * STEPS * VOCAB;      // [B, T] as float

    Ws* ws = (Ws*)d_ws;

    for (int t = 0; t <= STEPS; ++t) {
        hipLaunchKernelGGL(k_gates, dim3(256), dim3(256), 0, stream,
                           embs, init, w_ih, w_hh, b_ih, b_hh, bos,
                           out_logits, out_preds, ws, t);
        if (t < STEPS) {
            hipLaunchKernelGGL(k_logits, dim3(LOG_BLOCKS), dim3(256), 0, stream,
                               W_out, b_out, w_hh, b_hh, ws, t);
        }
    }
}